// Round 2
// baseline (441.130 us; speedup 1.0000x reference)
//
#include <hip/hip_runtime.h>
#include <math.h>

#define NBATCH 32
#define NCH 16
#define HW 65536
#define SLICES1 16   // k_sums: 4096 px/block, 8 float2 iters, reg ping-pong
#define SLICES2 16   // k_pass2: 4096 px/block, 4 float4 iters, phase-interleaved
#define TPB 256

// ws layout (floats)
#define WS_SUMS_S 0      // [b][cls][ch] -> b*32 + cls*16 + ch   (1024)
#define WS_SUMS_T 1024   // (1024)
#define WS_N1     2048   // per-batch class-1 pixel count (32)
#define WS_LOSS   2080   // per-batch loss partials (32)
#define WS_FLOATS 2112

__device__ __forceinline__ float wave_sum(float v) {
#pragma unroll
  for (int off = 32; off > 0; off >>= 1) v += __shfl_down(v, off, 64);
  return v;
}

// grid (SLICES1, NBATCH, 2). z=0 -> S, z=1 -> T.
// Register double-buffer: compute on one buffer while the other buffer's 17
// loads are in flight, so each wave keeps ~16 loads outstanding for its whole
// lifetime (fixes the load duty-cycle problem: warm-L3 replays showed zero-HBM
// runs at identical duration -> latency-bound, not BW-bound).
__global__ __launch_bounds__(TPB, 3) void k_sums(const float* __restrict__ S,
                                                 const float* __restrict__ T,
                                                 const int* __restrict__ tgt,
                                                 float* __restrict__ ws) {
  const int b = blockIdx.y;
  const int slice = blockIdx.x;
  const int which = blockIdx.z;  // uniform
  const int tid = threadIdx.x;
  const int lane = tid & 63, wid = tid >> 6;

  const float* Xb = (which ? T : S) + (size_t)b * NCH * HW;
  const int* tb = tgt + (size_t)b * HW;
  float* dst = ws + (which ? WS_SUMS_T : WS_SUMS_S) + b * 32;

  const int base = slice * (HW / SLICES1) + tid * 2;  // + it*(TPB*2)

  float c0s[NCH], c1s[NCH];
#pragma unroll
  for (int c = 0; c < NCH; ++c) { c0s[c] = 0.f; c1s[c] = 0.f; }
  float n1 = 0.f;

  float2 bufA[NCH], bufB[NCH];
  int2 tvA, tvB;

#define KS_LOAD(BUF, TV, IT) do { \
    const int p_ = base + (IT) * (TPB * 2); \
    TV = *(const int2*)(tb + p_); \
    _Pragma("unroll") \
    for (int c = 0; c < NCH; ++c) BUF[c] = *(const float2*)(Xb + (size_t)c * HW + p_); \
  } while (0)

#define KS_COMP(BUF, TV) do { \
    const float m0 = (TV.x == 1) ? 1.f : 0.f; \
    const float m1 = (TV.y == 1) ? 1.f : 0.f; \
    n1 += m0 + m1; \
    float s0a = 0.f, s0b = 0.f, s1a = 0.f, s1b = 0.f; \
    _Pragma("unroll") \
    for (int c = 0; c < NCH; c += 2) { \
      s0a = fmaf(BUF[c].x, BUF[c].x, s0a); \
      s1a = fmaf(BUF[c].y, BUF[c].y, s1a); \
      s0b = fmaf(BUF[c + 1].x, BUF[c + 1].x, s0b); \
      s1b = fmaf(BUF[c + 1].y, BUF[c + 1].y, s1b); \
    } \
    const float i0 = 1.f / fmaxf(sqrtf(s0a + s0b), 1e-12f); \
    const float i1 = 1.f / fmaxf(sqrtf(s1a + s1b), 1e-12f); \
    _Pragma("unroll") \
    for (int c = 0; c < NCH; ++c) { \
      const float f0 = BUF[c].x * i0, f1 = BUF[c].y * i1; \
      const float t_ = f0 + f1; \
      const float m_ = fmaf(f0, m0, f1 * m1); \
      c1s[c] += m_; \
      c0s[c] += t_ - m_; \
    } \
  } while (0)

  // 8 iterations, ping-pong: every compute phase covers the other buffer's loads
  KS_LOAD(bufA, tvA, 0);
  KS_LOAD(bufB, tvB, 1);
  KS_COMP(bufA, tvA);  KS_LOAD(bufA, tvA, 2);
  KS_COMP(bufB, tvB);  KS_LOAD(bufB, tvB, 3);
  KS_COMP(bufA, tvA);  KS_LOAD(bufA, tvA, 4);
  KS_COMP(bufB, tvB);  KS_LOAD(bufB, tvB, 5);
  KS_COMP(bufA, tvA);  KS_LOAD(bufA, tvA, 6);
  KS_COMP(bufB, tvB);  KS_LOAD(bufB, tvB, 7);
  KS_COMP(bufA, tvA);
  KS_COMP(bufB, tvB);

#undef KS_LOAD
#undef KS_COMP

#pragma unroll
  for (int c = 0; c < NCH; ++c) { c0s[c] = wave_sum(c0s[c]); c1s[c] = wave_sum(c1s[c]); }
  n1 = wave_sum(n1);

  __shared__ float red[4][36];
  if (lane == 0) {
#pragma unroll
    for (int c = 0; c < NCH; ++c) { red[wid][c] = c0s[c]; red[wid][16 + c] = c1s[c]; }
    red[wid][32] = n1;
  }
  __syncthreads();
  if (tid < 33) {
    const float v = red[0][tid] + red[1][tid] + red[2][tid] + red[3][tid];
    if (tid < 32) atomicAdd(dst + tid, v);          // dst[cls*16+ch]
    else if (which == 0) atomicAdd(ws + WS_N1 + b, v);
  }
}

// per-pixel pcsim given ss, raw dots vs class means, target, mean norms
__device__ __forceinline__ float pc_one(float ss, float d0, float d1, int t,
                                        float nm0, float nm1) {
  const float n = sqrtf(ss);
  const float inv = 1.f / fmaxf(n, 1e-12f);
  const float na = n * inv;  // == |feat| after normalize
  const float c0 = (d0 * inv) / fmaxf(na * nm0, 1e-8f);
  const float c1 = (d1 * inv) / fmaxf(na * nm1, 1e-8f);
  return expf((t == 1) ? (c1 - c0) : (c0 - c1));
}

// grid (SLICES2, NBATCH); 4 float4 iters; phase interleave: each stream's
// loads are covered by the other stream's compute phase. Iter-0 loads are
// issued before the sm preamble so the ws reads + barriers hide their latency.
__global__ __launch_bounds__(TPB, 2) void k_pass2(const float* __restrict__ S,
                                                  const float* __restrict__ T,
                                                  const int* __restrict__ tgt,
                                                  float* __restrict__ ws) {
  __shared__ __align__(16) float sm[72];  // [0..63] means, [64..67] mean norms
  __shared__ float red[4];
  const int b = blockIdx.y;
  const int slice = blockIdx.x;
  const int tid = threadIdx.x;

  const int base = slice * (HW / SLICES2) + tid * 4;  // + it*(TPB*4)
  const float* Sb = S + (size_t)b * NCH * HW;
  const float* Tb = T + (size_t)b * NCH * HW;
  const int* tb = tgt + (size_t)b * HW;

  float4 Sx[NCH], Tx[NCH];
  int4 tvA, tvB;

#define P2_LTV(TV, IT) TV = *(const int4*)(tb + base + (IT) * (TPB * 4))
#define P2_LS(IT) do { const int p_ = base + (IT) * (TPB * 4); \
    _Pragma("unroll") \
    for (int c = 0; c < NCH; ++c) Sx[c] = *(const float4*)(Sb + (size_t)c * HW + p_); \
  } while (0)
#define P2_LT(IT) do { const int p_ = base + (IT) * (TPB * 4); \
    _Pragma("unroll") \
    for (int c = 0; c < NCH; ++c) Tx[c] = *(const float4*)(Tb + (size_t)c * HW + p_); \
  } while (0)

  // prologue: issue iter-0 loads, then hide their latency under the preamble
  P2_LTV(tvA, 0);
  P2_LS(0);
  P2_LT(0);

  if (tid < 64) {
    const int t = tid >> 5, cls = (tid >> 4) & 1, ch = tid & 15;
    const float n1v = ws[WS_N1 + b];
    const float cnt = (cls ? n1v : ((float)HW - n1v)) + 1e-6f;
    const float s = ws[(t ? WS_SUMS_T : WS_SUMS_S) + b * 32 + cls * 16 + ch];
    sm[tid] = s / cnt;
  }
  __syncthreads();
  if (tid < 4) {  // tid = t*2+cls
    float ss = 0.f;
    const int base_ = (tid >> 1) * 32 + (tid & 1) * 16;
#pragma unroll
    for (int c = 0; c < NCH; ++c) { const float v = sm[base_ + c]; ss = fmaf(v, v, ss); }
    sm[64 + tid] = sqrtf(ss);
  }
  __syncthreads();

  const float4* smq = (const float4*)sm;  // b128 LDS reads of the weights
  const float nmS0 = sm[64], nmS1 = sm[65], nmT0 = sm[66], nmT1 = sm[67];

  float lacc = 0.f;
  float pcS0, pcS1, pcS2, pcS3;

#define P2_ACC(X, W0, W1) do { \
    ssv.x = fmaf(X.x, X.x, ssv.x); ssv.y = fmaf(X.y, X.y, ssv.y); \
    ssv.z = fmaf(X.z, X.z, ssv.z); ssv.w = fmaf(X.w, X.w, ssv.w); \
    d0.x = fmaf(X.x, W0, d0.x); d0.y = fmaf(X.y, W0, d0.y); \
    d0.z = fmaf(X.z, W0, d0.z); d0.w = fmaf(X.w, W0, d0.w); \
    d1.x = fmaf(X.x, W1, d1.x); d1.y = fmaf(X.y, W1, d1.y); \
    d1.z = fmaf(X.z, W1, d1.z); d1.w = fmaf(X.w, W1, d1.w); \
  } while (0)

#define P2_COMPS(TV) do { \
    float4 ssv = {0, 0, 0, 0}, d0 = {0, 0, 0, 0}, d1 = {0, 0, 0, 0}; \
    _Pragma("unroll") \
    for (int c4 = 0; c4 < 4; ++c4) { \
      const float4 w0 = smq[c4], w1 = smq[4 + c4]; \
      P2_ACC(Sx[4 * c4 + 0], w0.x, w1.x); P2_ACC(Sx[4 * c4 + 1], w0.y, w1.y); \
      P2_ACC(Sx[4 * c4 + 2], w0.z, w1.z); P2_ACC(Sx[4 * c4 + 3], w0.w, w1.w); \
    } \
    pcS0 = pc_one(ssv.x, d0.x, d1.x, TV.x, nmS0, nmS1); \
    pcS1 = pc_one(ssv.y, d0.y, d1.y, TV.y, nmS0, nmS1); \
    pcS2 = pc_one(ssv.z, d0.z, d1.z, TV.z, nmS0, nmS1); \
    pcS3 = pc_one(ssv.w, d0.w, d1.w, TV.w, nmS0, nmS1); \
  } while (0)

#define P2_COMPT(TV) do { \
    float4 ssv = {0, 0, 0, 0}, d0 = {0, 0, 0, 0}, d1 = {0, 0, 0, 0}; \
    _Pragma("unroll") \
    for (int c4 = 0; c4 < 4; ++c4) { \
      const float4 w0 = smq[8 + c4], w1 = smq[12 + c4]; \
      P2_ACC(Tx[4 * c4 + 0], w0.x, w1.x); P2_ACC(Tx[4 * c4 + 1], w0.y, w1.y); \
      P2_ACC(Tx[4 * c4 + 2], w0.z, w1.z); P2_ACC(Tx[4 * c4 + 3], w0.w, w1.w); \
    } \
    const float pcT0 = pc_one(ssv.x, d0.x, d1.x, TV.x, nmT0, nmT1); \
    const float pcT1 = pc_one(ssv.y, d0.y, d1.y, TV.y, nmT0, nmT1); \
    const float pcT2 = pc_one(ssv.z, d0.z, d1.z, TV.z, nmT0, nmT1); \
    const float pcT3 = pc_one(ssv.w, d0.w, d1.w, TV.w, nmT0, nmT1); \
    const float e0 = pcS0 - pcT0, e1 = pcS1 - pcT1; \
    const float e2 = pcS2 - pcT2, e3 = pcS3 - pcT3; \
    lacc += e0 * e0 + e1 * e1 + e2 * e2 + e3 * e3; \
  } while (0)

  // it0
  P2_COMPS(tvA);  P2_LS(1);  P2_LTV(tvB, 1);
  P2_COMPT(tvA);  P2_LT(1);
  // it1
  P2_COMPS(tvB);  P2_LS(2);  P2_LTV(tvA, 2);
  P2_COMPT(tvB);  P2_LT(2);
  // it2
  P2_COMPS(tvA);  P2_LS(3);  P2_LTV(tvB, 3);
  P2_COMPT(tvA);  P2_LT(3);
  // it3
  P2_COMPS(tvB);
  P2_COMPT(tvB);

#undef P2_LTV
#undef P2_LS
#undef P2_LT
#undef P2_ACC
#undef P2_COMPS
#undef P2_COMPT

  lacc = wave_sum(lacc);
  if ((tid & 63) == 0) red[tid >> 6] = lacc;
  __syncthreads();
  if (tid == 0)
    atomicAdd(ws + WS_LOSS + b, red[0] + red[1] + red[2] + red[3]);
}

// one wave: parallel read of the 32 per-batch partials + shuffle reduce
__global__ void k_final(const float* __restrict__ ws, float* __restrict__ out) {
  const int lane = threadIdx.x & 63;
  float v = (lane < NBATCH) ? ws[WS_LOSS + lane] : 0.f;
  v = wave_sum(v);
  if (lane == 0) out[0] = v * (1.f / 2097152.f);  // N = 32*256*256 = 2^21, exact
}

extern "C" void kernel_launch(void* const* d_in, const int* in_sizes, int n_in,
                              void* d_out, int out_size, void* d_ws, size_t ws_size,
                              hipStream_t stream) {
  const float* S = (const float*)d_in[0];
  const float* T = (const float*)d_in[1];
  const int* tgt = (const int*)d_in[2];
  float* ws = (float*)d_ws;
  float* out = (float*)d_out;

  hipMemsetAsync(d_ws, 0, WS_FLOATS * sizeof(float), stream);
  dim3 g1(SLICES1, NBATCH, 2);
  k_sums<<<g1, TPB, 0, stream>>>(S, T, tgt, ws);
  dim3 g2(SLICES2, NBATCH);
  k_pass2<<<g2, TPB, 0, stream>>>(S, T, tgt, ws);
  k_final<<<1, 64, 0, stream>>>(ws, out);
}

// Round 3
// 335.102 us; speedup vs baseline: 1.3164x; 1.3164x over previous
//
#include <hip/hip_runtime.h>
#include <math.h>

#define NBATCH 32
#define NCH 16
#define HW 65536
#define SLICES1 32   // k_sums: 2048 px/block, 2 float4 iters
#define SLICES2 32   // k_pass2: 2048 px/block, 4 float2 iters (S+T fused)
#define TPB 256

// ws layout (floats)
#define WS_SUMS_S 0      // [b][cls][ch] -> b*32 + cls*16 + ch   (1024)
#define WS_SUMS_T 1024   // (1024)
#define WS_N1     2048   // per-batch class-1 pixel count (32)
#define WS_LOSS   2080   // per-batch loss partials (32)
#define WS_FLOATS 2112

__device__ __forceinline__ float wave_sum(float v) {
#pragma unroll
  for (int off = 32; off > 0; off >>= 1) v += __shfl_down(v, off, 64);
  return v;
}

// grid (SLICES1, NBATCH, 2). z=0 -> S, z=1 -> T.
// Key changes vs previous rounds:
//  - channel ROTATION: each wave starts its walk of the 16 channel streams at
//    a different phase. The streams are 256KB-strided (power of 2) and alias
//    to the same memory channel/slice; rotation decorrelates concurrent waves.
//  - LDS-transpose reduction tail: replaces 33 serially-dependent 6-deep
//    shuffle chains (~200 dependent DS ops) with conflict-free writes + 32
//    pipelined independent reads + 3 shuffles.
//  - immediate-consume loads, no big double-buffer arrays (round-2 spilled:
//    WRITE_SIZE 170MB of scratch traffic).
__global__ __launch_bounds__(TPB) void k_sums(const float* __restrict__ S,
                                              const float* __restrict__ T,
                                              const int* __restrict__ tgt,
                                              float* __restrict__ ws) {
  const int b = blockIdx.y;
  const int slice = blockIdx.x;
  const int which = blockIdx.z;  // uniform
  const int tid = threadIdx.x;
  const int wid = tid >> 6;

  const float* Xb = (which ? T : S) + (size_t)b * NCH * HW;
  const int* tb = tgt + (size_t)b * HW;
  float* dst = ws + (which ? WS_SUMS_T : WS_SUMS_S) + b * 32;

  // rotation phase: differs across waves, slices, batches, and S/T halves
  const int off = (wid + ((slice & 3) << 2) + b + (which << 3)) & 15;

  const int base = slice * (HW / SLICES1) + tid * 4;  // + it*(TPB*4)

  float acc0[NCH], acc1[NCH];  // acc*[i] belongs to channel (i+off)&15
#pragma unroll
  for (int i = 0; i < NCH; ++i) { acc0[i] = 0.f; acc1[i] = 0.f; }
  float n1 = 0.f;

  for (int it = 0; it < 2; ++it) {
    const int p = base + it * (TPB * 4);
    const int4 tv = *(const int4*)(tb + p);
    float4 x[NCH];
#pragma unroll
    for (int i = 0; i < NCH; ++i) {
      const int cc = (i + off) & 15;
      x[i] = *(const float4*)(Xb + (size_t)cc * HW + p);
    }

    const float m0 = (tv.x == 1) ? 1.f : 0.f;
    const float m1 = (tv.y == 1) ? 1.f : 0.f;
    const float m2 = (tv.z == 1) ? 1.f : 0.f;
    const float m3 = (tv.w == 1) ? 1.f : 0.f;
    n1 += (m0 + m1) + (m2 + m3);

    // per-pixel sum of squares over ALL channels (order irrelevant)
    float s0a = 0.f, s0b = 0.f, s1a = 0.f, s1b = 0.f;
    float s2a = 0.f, s2b = 0.f, s3a = 0.f, s3b = 0.f;
#pragma unroll
    for (int i = 0; i < NCH; i += 2) {
      s0a = fmaf(x[i].x, x[i].x, s0a);   s0b = fmaf(x[i + 1].x, x[i + 1].x, s0b);
      s1a = fmaf(x[i].y, x[i].y, s1a);   s1b = fmaf(x[i + 1].y, x[i + 1].y, s1b);
      s2a = fmaf(x[i].z, x[i].z, s2a);   s2b = fmaf(x[i + 1].z, x[i + 1].z, s2b);
      s3a = fmaf(x[i].w, x[i].w, s3a);   s3b = fmaf(x[i + 1].w, x[i + 1].w, s3b);
    }
    const float i0 = 1.f / fmaxf(sqrtf(s0a + s0b), 1e-12f);
    const float i1 = 1.f / fmaxf(sqrtf(s1a + s1b), 1e-12f);
    const float i2 = 1.f / fmaxf(sqrtf(s2a + s2b), 1e-12f);
    const float i3 = 1.f / fmaxf(sqrtf(s3a + s3b), 1e-12f);

#pragma unroll
    for (int i = 0; i < NCH; ++i) {
      const float f0 = x[i].x * i0, f1 = x[i].y * i1;
      const float f2 = x[i].z * i2, f3 = x[i].w * i3;
      const float t_ = (f0 + f1) + (f2 + f3);
      const float m_ = fmaf(f0, m0, fmaf(f1, m1, fmaf(f2, m2, f3 * m3)));
      acc1[i] += m_;
      acc0[i] += t_ - m_;
    }
  }

  // ---- LDS-transpose reduction: rows = cls*16+ch (matches dst layout) ----
  __shared__ float lds[32][TPB + 1];  // 32 x 257 floats = 32.9 KB
  __shared__ float redn[4];
#pragma unroll
  for (int i = 0; i < NCH; ++i) {
    const int r = (i + off) & 15;   // runtime LDS address resolves the rotation
    lds[r][tid] = acc0[i];
    lds[16 + r][tid] = acc1[i];
  }
  n1 = wave_sum(n1);  // single cheap chain
  if ((tid & 63) == 0) redn[wid] = n1;
  __syncthreads();

  const int row = tid >> 3, seg = tid & 7;  // 32 rows x 8 segments
  float s = 0.f;
#pragma unroll
  for (int k0 = 0; k0 < 32; ++k0) {
    const int k = (k0 + seg * 4) & 31;  // swizzle: <=2-way bank aliasing (free)
    s += lds[row][seg * 32 + k];
  }
  s += __shfl_down(s, 4, 8);
  s += __shfl_down(s, 2, 8);
  s += __shfl_down(s, 1, 8);
  if (seg == 0) atomicAdd(dst + row, s);
  if (tid == 0 && which == 0)
    atomicAdd(ws + WS_N1 + b, redn[0] + redn[1] + redn[2] + redn[3]);
}

// per-pixel pcsim given ss, raw dots vs class means, target, mean norms
__device__ __forceinline__ float pc_one(float ss, float d0, float d1, int t,
                                        float nm0, float nm1) {
  const float n = sqrtf(ss);
  const float inv = 1.f / fmaxf(n, 1e-12f);
  const float na = n * inv;  // == |feat| after normalize
  const float c0 = (d0 * inv) / fmaxf(na * nm0, 1e-8f);
  const float c1 = (d1 * inv) / fmaxf(na * nm1, 1e-8f);
  return expf((t == 1) ? (c1 - c0) : (c0 - c1));
}

// grid (SLICES2, NBATCH). S+T fused float2 iterations with rotated channels.
// T loads are issued before S-compute, so S-compute covers T latency via
// incremental vmcnt. Per-pixel accumulators -> rotation needs no re-indexing.
__global__ __launch_bounds__(TPB) void k_pass2(const float* __restrict__ S,
                                               const float* __restrict__ T,
                                               const int* __restrict__ tgt,
                                               float* __restrict__ ws) {
  __shared__ __align__(16) float sm[72];  // [0..63] means, [64..67] mean norms
  __shared__ float red[4];
  const int b = blockIdx.y;
  const int slice = blockIdx.x;
  const int tid = threadIdx.x;
  const int wid = tid >> 6;

  const int offS = (wid + ((slice & 3) << 2) + b) & 15;
  const int offT = (offS + 8) & 15;

  const int base = slice * (HW / SLICES2) + tid * 2;  // + it*(TPB*2)
  const float* Sb = S + (size_t)b * NCH * HW;
  const float* Tb = T + (size_t)b * NCH * HW;
  const int* tb = tgt + (size_t)b * HW;

  if (tid < 64) {
    const int t = tid >> 5, cls = (tid >> 4) & 1, ch = tid & 15;
    const float n1v = ws[WS_N1 + b];
    const float cnt = (cls ? n1v : ((float)HW - n1v)) + 1e-6f;
    const float s = ws[(t ? WS_SUMS_T : WS_SUMS_S) + b * 32 + cls * 16 + ch];
    sm[tid] = s / cnt;
  }
  __syncthreads();
  if (tid < 4) {  // tid = t*2+cls
    float ss = 0.f;
    const int base_ = (tid >> 1) * 32 + (tid & 1) * 16;
#pragma unroll
    for (int c = 0; c < NCH; ++c) { const float v = sm[base_ + c]; ss = fmaf(v, v, ss); }
    sm[64 + tid] = sqrtf(ss);
  }
  __syncthreads();

  const float nmS0 = sm[64], nmS1 = sm[65], nmT0 = sm[66], nmT1 = sm[67];
  float lacc = 0.f;

  for (int it = 0; it < 4; ++it) {
    const int p = base + it * (TPB * 2);
    const int2 tv = *(const int2*)(tb + p);
    float2 xs[NCH], xt[NCH];
#pragma unroll
    for (int i = 0; i < NCH; ++i)
      xs[i] = *(const float2*)(Sb + (size_t)((i + offS) & 15) * HW + p);
#pragma unroll
    for (int i = 0; i < NCH; ++i)
      xt[i] = *(const float2*)(Tb + (size_t)((i + offT) & 15) * HW + p);

    // ---- S (T loads still in flight) ----
    float ss0 = 0.f, ss1 = 0.f, d00 = 0.f, d01 = 0.f, d10 = 0.f, d11 = 0.f;
#pragma unroll
    for (int i = 0; i < NCH; ++i) {
      const int cc = (i + offS) & 15;
      const float w0 = sm[cc], w1 = sm[16 + cc];  // wave-uniform -> broadcast
      ss0 = fmaf(xs[i].x, xs[i].x, ss0); ss1 = fmaf(xs[i].y, xs[i].y, ss1);
      d00 = fmaf(xs[i].x, w0, d00);      d01 = fmaf(xs[i].y, w0, d01);
      d10 = fmaf(xs[i].x, w1, d10);      d11 = fmaf(xs[i].y, w1, d11);
    }
    const float pcS0 = pc_one(ss0, d00, d10, tv.x, nmS0, nmS1);
    const float pcS1 = pc_one(ss1, d01, d11, tv.y, nmS0, nmS1);

    // ---- T ----
    ss0 = 0.f; ss1 = 0.f; d00 = 0.f; d01 = 0.f; d10 = 0.f; d11 = 0.f;
#pragma unroll
    for (int i = 0; i < NCH; ++i) {
      const int cc = (i + offT) & 15;
      const float w0 = sm[32 + cc], w1 = sm[48 + cc];
      ss0 = fmaf(xt[i].x, xt[i].x, ss0); ss1 = fmaf(xt[i].y, xt[i].y, ss1);
      d00 = fmaf(xt[i].x, w0, d00);      d01 = fmaf(xt[i].y, w0, d01);
      d10 = fmaf(xt[i].x, w1, d10);      d11 = fmaf(xt[i].y, w1, d11);
    }
    const float pcT0 = pc_one(ss0, d00, d10, tv.x, nmT0, nmT1);
    const float pcT1 = pc_one(ss1, d01, d11, tv.y, nmT0, nmT1);

    const float e0 = pcS0 - pcT0, e1 = pcS1 - pcT1;
    lacc += e0 * e0 + e1 * e1;
  }

  lacc = wave_sum(lacc);
  if ((tid & 63) == 0) red[tid >> 6] = lacc;
  __syncthreads();
  if (tid == 0)
    atomicAdd(ws + WS_LOSS + b, red[0] + red[1] + red[2] + red[3]);
}

// one wave: parallel read of the 32 per-batch partials + shuffle reduce
__global__ void k_final(const float* __restrict__ ws, float* __restrict__ out) {
  const int lane = threadIdx.x & 63;
  float v = (lane < NBATCH) ? ws[WS_LOSS + lane] : 0.f;
  v = wave_sum(v);
  if (lane == 0) out[0] = v * (1.f / 2097152.f);  // N = 32*256*256 = 2^21, exact
}

extern "C" void kernel_launch(void* const* d_in, const int* in_sizes, int n_in,
                              void* d_out, int out_size, void* d_ws, size_t ws_size,
                              hipStream_t stream) {
  const float* S = (const float*)d_in[0];
  const float* T = (const float*)d_in[1];
  const int* tgt = (const int*)d_in[2];
  float* ws = (float*)d_ws;
  float* out = (float*)d_out;

  hipMemsetAsync(d_ws, 0, WS_FLOATS * sizeof(float), stream);
  dim3 g1(SLICES1, NBATCH, 2);
  k_sums<<<g1, TPB, 0, stream>>>(S, T, tgt, ws);
  dim3 g2(SLICES2, NBATCH);
  k_pass2<<<g2, TPB, 0, stream>>>(S, T, tgt, ws);
  k_final<<<1, 64, 0, stream>>>(ws, out);
}

// Round 4
// 326.511 us; speedup vs baseline: 1.3510x; 1.0263x over previous
//
#include <hip/hip_runtime.h>
#include <math.h>

#define NBATCH 32
#define NCH 16
#define HW 65536
#define SLICES1 64   // k_sums: 1024 px/block, LDS-staged
#define SLICES2 32   // k_pass2: 2048 px/block, 4 float2 iters (NT loads)
#define TPB 256

// ws layout (floats)
#define WS_SUMS_S 0      // [b][cls][ch] -> b*32 + cls*16 + ch   (1024)
#define WS_SUMS_T 1024   // (1024)
#define WS_N1     2048   // per-batch class-1 pixel count (32)
#define WS_LOSS   2080   // per-batch loss partials (32)
#define WS_FLOATS 2112

typedef float v2f __attribute__((ext_vector_type(2)));

__device__ __forceinline__ float wave_sum(float v) {
#pragma unroll
  for (int off = 32; off > 0; off >>= 1) v += __shfl_down(v, off, 64);
  return v;
}

// async global->LDS, 16B per lane; LDS dest is wave-uniform base + lane*16
__device__ __forceinline__ void async_copy16(const float* g, float* l) {
  __builtin_amdgcn_global_load_lds(
      (const __attribute__((address_space(1))) void*)g,
      (__attribute__((address_space(3))) void*)l, 16, 0, 0);
}

// grid (SLICES1, NBATCH, 2). z=0 -> S, z=1 -> T.
// THEORY: all prior variants issue 16 concurrent 256KB-strided streams per
// wave; identical addr bits [7:17] put them in the same L1 set group and the
// per-set miss pipeline serializes (warm-L3 == cold-HBM duration => the cap
// is CU-side, common to both fill paths). Fix: each wave loads 4 WHOLE 4KB
// channel rows contiguously (memcpy-shaped, like the 6.3TB/s m13 pattern)
// into LDS via async global_load_lds, with 1KB chunk-phase rotation to
// spread concurrent rows across set groups. Compute then reads pixel-major
// from LDS (conflict-free).
__global__ __launch_bounds__(TPB) void k_sums(const float* __restrict__ S,
                                              const float* __restrict__ T,
                                              const int* __restrict__ tgt,
                                              float* __restrict__ ws) {
  __shared__ __align__(16) float smem[16 * 1024];  // 64KB: xs[16][1024], reused by tail
  const int b = blockIdx.y;
  const int slice = blockIdx.x;
  const int which = blockIdx.z;  // uniform
  const int tid = threadIdx.x;
  const int lane = tid & 63, wid = tid >> 6;

  const float* Xb = (which ? T : S) + (size_t)b * NCH * HW;
  const int* tb = tgt + (size_t)b * HW;
  float* dst = ws + (which ? WS_SUMS_T : WS_SUMS_S) + b * 32;

  const int tilebase = slice * 1024;

  // ---- phase A: stage 16 channel rows (4KB each) into LDS ----
  // wave w loads rows 4w..4w+3; row j of the wave walks its 4 1KB chunks in
  // phase (k+j)&3 so concurrent streams differ in addr bits [10:11].
  const int4 tv = *(const int4*)(tb + tilebase + tid * 4);  // reg load, used in B
#pragma unroll
  for (int j = 0; j < 4; ++j) {
    const int r = (wid << 2) + j;
#pragma unroll
    for (int k = 0; k < 4; ++k) {
      const int chunk = (k + j) & 3;
      async_copy16(Xb + (size_t)r * HW + tilebase + chunk * 256 + lane * 4,
                   &smem[r * 1024 + chunk * 256]);
    }
  }
  __syncthreads();  // drains vmcnt -> LDS tile complete

  // ---- phase B: pixel-major compute from LDS (4 px per thread) ----
  float4 x[NCH];
#pragma unroll
  for (int c = 0; c < NCH; ++c) x[c] = *(const float4*)&smem[c * 1024 + tid * 4];

  const float m0 = (tv.x == 1) ? 1.f : 0.f;
  const float m1 = (tv.y == 1) ? 1.f : 0.f;
  const float m2 = (tv.z == 1) ? 1.f : 0.f;
  const float m3 = (tv.w == 1) ? 1.f : 0.f;
  float n1 = (m0 + m1) + (m2 + m3);

  float s0a = 0.f, s0b = 0.f, s1a = 0.f, s1b = 0.f;
  float s2a = 0.f, s2b = 0.f, s3a = 0.f, s3b = 0.f;
#pragma unroll
  for (int i = 0; i < NCH; i += 2) {
    s0a = fmaf(x[i].x, x[i].x, s0a);   s0b = fmaf(x[i + 1].x, x[i + 1].x, s0b);
    s1a = fmaf(x[i].y, x[i].y, s1a);   s1b = fmaf(x[i + 1].y, x[i + 1].y, s1b);
    s2a = fmaf(x[i].z, x[i].z, s2a);   s2b = fmaf(x[i + 1].z, x[i + 1].z, s2b);
    s3a = fmaf(x[i].w, x[i].w, s3a);   s3b = fmaf(x[i + 1].w, x[i + 1].w, s3b);
  }
  const float i0 = 1.f / fmaxf(sqrtf(s0a + s0b), 1e-12f);
  const float i1 = 1.f / fmaxf(sqrtf(s1a + s1b), 1e-12f);
  const float i2 = 1.f / fmaxf(sqrtf(s2a + s2b), 1e-12f);
  const float i3 = 1.f / fmaxf(sqrtf(s3a + s3b), 1e-12f);

  float acc0[NCH], acc1[NCH];
#pragma unroll
  for (int i = 0; i < NCH; ++i) {
    const float f0 = x[i].x * i0, f1 = x[i].y * i1;
    const float f2 = x[i].z * i2, f3 = x[i].w * i3;
    const float t_ = (f0 + f1) + (f2 + f3);
    const float m_ = fmaf(f0, m0, fmaf(f1, m1, fmaf(f2, m2, f3 * m3)));
    acc1[i] = m_;
    acc0[i] = t_ - m_;
  }
  n1 = wave_sum(n1);

  __syncthreads();  // phase-B LDS reads done; safe to reuse smem for the tail

  // ---- tail: LDS-transpose reduction (proven conflict-free in round 3) ----
  float (*red)[257] = (float(*)[257])smem;   // 32*257 floats = 32.9KB < 64KB
  float* redn = smem + 16000;                // beyond the red region
#pragma unroll
  for (int i = 0; i < NCH; ++i) {
    red[i][tid] = acc0[i];
    red[16 + i][tid] = acc1[i];
  }
  if (lane == 0) redn[wid] = n1;
  __syncthreads();

  const int row = tid >> 3, seg = tid & 7;  // 32 rows x 8 segments
  float s = 0.f;
#pragma unroll
  for (int k0 = 0; k0 < 32; ++k0) {
    const int k = (k0 + seg * 4) & 31;  // bank-swizzle: conflict-free
    s += red[row][seg * 32 + k];
  }
  s += __shfl_down(s, 4, 8);
  s += __shfl_down(s, 2, 8);
  s += __shfl_down(s, 1, 8);
  if (seg == 0) atomicAdd(dst + row, s);
  if (tid == 0 && which == 0)
    atomicAdd(ws + WS_N1 + b, redn[0] + redn[1] + redn[2] + redn[3]);
}

// per-pixel pcsim given ss, raw dots vs class means, target, mean norms
__device__ __forceinline__ float pc_one(float ss, float d0, float d1, int t,
                                        float nm0, float nm1) {
  const float n = sqrtf(ss);
  const float inv = 1.f / fmaxf(n, 1e-12f);
  const float na = n * inv;  // == |feat| after normalize
  const float c0 = (d0 * inv) / fmaxf(na * nm0, 1e-8f);
  const float c1 = (d1 * inv) / fmaxf(na * nm1, 1e-8f);
  return expf((t == 1) ? (c1 - c0) : (c0 - c1));
}

// grid (SLICES2, NBATCH). Round-3 structure, but channel loads are
// NON-TEMPORAL (nt flag: no L1 allocation). A/B vs k_sums' staging: if the
// L1 miss/allocate pipeline is the serializer, nt alone should fix this one.
__global__ __launch_bounds__(TPB) void k_pass2(const float* __restrict__ S,
                                               const float* __restrict__ T,
                                               const int* __restrict__ tgt,
                                               float* __restrict__ ws) {
  __shared__ __align__(16) float sm[72];  // [0..63] means, [64..67] mean norms
  __shared__ float red[4];
  const int b = blockIdx.y;
  const int slice = blockIdx.x;
  const int tid = threadIdx.x;
  const int wid = tid >> 6;

  const int offS = (wid + ((slice & 3) << 2) + b) & 15;
  const int offT = (offS + 8) & 15;

  const int base = slice * (HW / SLICES2) + tid * 2;  // + it*(TPB*2)
  const float* Sb = S + (size_t)b * NCH * HW;
  const float* Tb = T + (size_t)b * NCH * HW;
  const int* tb = tgt + (size_t)b * HW;

  if (tid < 64) {
    const int t = tid >> 5, cls = (tid >> 4) & 1, ch = tid & 15;
    const float n1v = ws[WS_N1 + b];
    const float cnt = (cls ? n1v : ((float)HW - n1v)) + 1e-6f;
    const float s = ws[(t ? WS_SUMS_T : WS_SUMS_S) + b * 32 + cls * 16 + ch];
    sm[tid] = s / cnt;
  }
  __syncthreads();
  if (tid < 4) {  // tid = t*2+cls
    float ss = 0.f;
    const int base_ = (tid >> 1) * 32 + (tid & 1) * 16;
#pragma unroll
    for (int c = 0; c < NCH; ++c) { const float v = sm[base_ + c]; ss = fmaf(v, v, ss); }
    sm[64 + tid] = sqrtf(ss);
  }
  __syncthreads();

  const float nmS0 = sm[64], nmS1 = sm[65], nmT0 = sm[66], nmT1 = sm[67];
  float lacc = 0.f;

  for (int it = 0; it < 4; ++it) {
    const int p = base + it * (TPB * 2);
    const int2 tv = *(const int2*)(tb + p);
    v2f xs[NCH], xt[NCH];
#pragma unroll
    for (int i = 0; i < NCH; ++i)
      xs[i] = __builtin_nontemporal_load(
          (const v2f*)(Sb + (size_t)((i + offS) & 15) * HW + p));
#pragma unroll
    for (int i = 0; i < NCH; ++i)
      xt[i] = __builtin_nontemporal_load(
          (const v2f*)(Tb + (size_t)((i + offT) & 15) * HW + p));

    // ---- S (T loads still in flight) ----
    float ss0 = 0.f, ss1 = 0.f, d00 = 0.f, d01 = 0.f, d10 = 0.f, d11 = 0.f;
#pragma unroll
    for (int i = 0; i < NCH; ++i) {
      const int cc = (i + offS) & 15;
      const float w0 = sm[cc], w1 = sm[16 + cc];  // wave-uniform -> broadcast
      ss0 = fmaf(xs[i].x, xs[i].x, ss0); ss1 = fmaf(xs[i].y, xs[i].y, ss1);
      d00 = fmaf(xs[i].x, w0, d00);      d01 = fmaf(xs[i].y, w0, d01);
      d10 = fmaf(xs[i].x, w1, d10);      d11 = fmaf(xs[i].y, w1, d11);
    }
    const float pcS0 = pc_one(ss0, d00, d10, tv.x, nmS0, nmS1);
    const float pcS1 = pc_one(ss1, d01, d11, tv.y, nmS0, nmS1);

    // ---- T ----
    ss0 = 0.f; ss1 = 0.f; d00 = 0.f; d01 = 0.f; d10 = 0.f; d11 = 0.f;
#pragma unroll
    for (int i = 0; i < NCH; ++i) {
      const int cc = (i + offT) & 15;
      const float w0 = sm[32 + cc], w1 = sm[48 + cc];
      ss0 = fmaf(xt[i].x, xt[i].x, ss0); ss1 = fmaf(xt[i].y, xt[i].y, ss1);
      d00 = fmaf(xt[i].x, w0, d00);      d01 = fmaf(xt[i].y, w0, d01);
      d10 = fmaf(xt[i].x, w1, d10);      d11 = fmaf(xt[i].y, w1, d11);
    }
    const float pcT0 = pc_one(ss0, d00, d10, tv.x, nmT0, nmT1);
    const float pcT1 = pc_one(ss1, d01, d11, tv.y, nmT0, nmT1);

    const float e0 = pcS0 - pcT0, e1 = pcS1 - pcT1;
    lacc += e0 * e0 + e1 * e1;
  }

  lacc = wave_sum(lacc);
  if ((tid & 63) == 0) red[tid >> 6] = lacc;
  __syncthreads();
  if (tid == 0)
    atomicAdd(ws + WS_LOSS + b, red[0] + red[1] + red[2] + red[3]);
}

// one wave: parallel read of the 32 per-batch partials + shuffle reduce
__global__ void k_final(const float* __restrict__ ws, float* __restrict__ out) {
  const int lane = threadIdx.x & 63;
  float v = (lane < NBATCH) ? ws[WS_LOSS + lane] : 0.f;
  v = wave_sum(v);
  if (lane == 0) out[0] = v * (1.f / 2097152.f);  // N = 32*256*256 = 2^21, exact
}

extern "C" void kernel_launch(void* const* d_in, const int* in_sizes, int n_in,
                              void* d_out, int out_size, void* d_ws, size_t ws_size,
                              hipStream_t stream) {
  const float* S = (const float*)d_in[0];
  const float* T = (const float*)d_in[1];
  const int* tgt = (const int*)d_in[2];
  float* ws = (float*)d_ws;
  float* out = (float*)d_out;

  hipMemsetAsync(d_ws, 0, WS_FLOATS * sizeof(float), stream);
  dim3 g1(SLICES1, NBATCH, 2);
  k_sums<<<g1, TPB, 0, stream>>>(S, T, tgt, ws);
  dim3 g2(SLICES2, NBATCH);
  k_pass2<<<g2, TPB, 0, stream>>>(S, T, tgt, ws);
  k_final<<<1, 64, 0, stream>>>(ws, out);
}